// Round 12
// baseline (155.881 us; speedup 1.0000x reference)
//
#include <hip/hip_runtime.h>
#include <cstdint>
#include <math.h>

// SoftmaxGaussian: out_mean/out_var over 10000 MC softmax samples with
// JAX threefry2x32-exact random draw (key(42), shape (512,16,10000)).
//
// Layout facts:
//   N = 512*16*10000 ; half = 40,960,000 = 256*16*10000
//   flat j=(b*16+k)*10000+s ; threefry block i: counters (i, i+half),
//   key (0,42) -> (z[j=i], z[j=i+half]) => one call yields (b,k,s) AND
//   (b+256,k,s).
//
// R12: scoreboard (harness clock): R10 145.0 is champion (R6-structure +
// tail-skip). Dead levers: issue cuts (~1%), wave count (R7/R9),
// granularity 512/256/128/64 (R4/R6/R11), spill-vs-residency (R5/R6).
// Floor arithmetic: threefry 34us + erfinv 31us + softmax 17us => ~110-130us
// achievable; kernel ~140. Last single-variable candidate: SPLIT=8
// (2048 blocks, 8/CU queued vs ~4 resident) for better CU packing/tail
// overlap. If flat, next round declares roofline.

typedef float f32x2 __attribute__((ext_vector_type(2)));

#define NSAMP 10000
#define HALF_N 40960000u
#define THREADS 256
#define WAVES (THREADS / 64)

#define LOG2E 1.44269504088896340736f
#define NLN2 -0.69314718055994530942f
#define SQRT_LN2 0.83255461115769775635f
#define TAIL_TH -7.2134752f  // -5/ln2: main path iff l = log2(1-x^2) > this

__device__ __forceinline__ uint32_t rotl32(uint32_t x, int r) {
    return __builtin_rotateleft32(x, (unsigned)r);  // v_alignbit_b32
}

// JAX threefry2x32, key = (0, 42)
__device__ __forceinline__ void tf2x32(uint32_t x0, uint32_t x1,
                                       uint32_t& o0, uint32_t& o1) {
    const uint32_t ks1 = 42u;
    const uint32_t ks2 = 0x1BD11BDAu ^ 42u;
    x1 += ks1;
#define TF_R(r) { x0 += x1; x1 = rotl32(x1, r); x1 ^= x0; }
    TF_R(13) TF_R(15) TF_R(26) TF_R(6)   x0 += ks1; x1 += ks2 + 1u;
    TF_R(17) TF_R(29) TF_R(16) TF_R(24)  x0 += ks2; x1 += 2u;
    TF_R(13) TF_R(15) TF_R(26) TF_R(6)                x1 += ks1 + 3u;
    TF_R(17) TF_R(29) TF_R(16) TF_R(24)  x0 += ks1; x1 += ks2 + 4u;
    TF_R(13) TF_R(15) TF_R(26) TF_R(6)   x0 += ks2; x1 += 5u;
#undef TF_R
    o0 = x0;
    o1 = x1;
}

// JAX uniform(lo=nextafter(-1,0), hi=1), packed pair; one rounding (= JAX).
__device__ __forceinline__ f32x2 u2_from_bits(uint32_t ba, uint32_t bb) {
    f32x2 f;
    f.x = __uint_as_float((ba >> 9) | 0x3F800000u);
    f.y = __uint_as_float((bb >> 9) | 0x3F800000u);
    f = f - (f32x2){1.0f, 1.0f};  // exact (Sterbenz)
    return __builtin_elementwise_fma(f, (f32x2){2.0f, 2.0f},
                                     (f32x2){-0.99999994f, -0.99999994f});
}

// XLA's ErfInv f32 (Giles 2012), packed pair, wave-uniform tail skip.
// Values identical to the branchless version.
__device__ __forceinline__ f32x2 erfinv2(f32x2 x) {
    f32x2 t = __builtin_elementwise_fma(-x, x, (f32x2){1.0f, 1.0f});
    f32x2 l;
    l.x = __builtin_amdgcn_logf(t.x);
    l.y = __builtin_amdgcn_logf(t.y);
    f32x2 wm = __builtin_elementwise_fma((f32x2){NLN2, NLN2}, l,
                                         (f32x2){-2.5f, -2.5f});
#define P9(P, W, C) P = __builtin_elementwise_fma(P, W, (f32x2){C, C});
    f32x2 p1 = {2.81022636e-08f, 2.81022636e-08f};
    P9(p1, wm, 3.43273939e-07f)
    P9(p1, wm, -3.5233877e-06f)
    P9(p1, wm, -4.39150654e-06f)
    P9(p1, wm, 0.00021858087f)
    P9(p1, wm, -0.00125372503f)
    P9(p1, wm, -0.00417768164f)
    P9(p1, wm, 0.246640727f)
    P9(p1, wm, 1.50140941f)
    f32x2 p = p1;
    if (__any((l.x < TAIL_TH) || (l.y < TAIL_TH))) {
        f32x2 sq;
        sq.x = __builtin_amdgcn_sqrtf(-l.x);
        sq.y = __builtin_amdgcn_sqrtf(-l.y);
        f32x2 wt = __builtin_elementwise_fma((f32x2){SQRT_LN2, SQRT_LN2}, sq,
                                             (f32x2){-3.0f, -3.0f});
        f32x2 p2 = {-0.000200214257f, -0.000200214257f};
        P9(p2, wt, 0.000100950558f)
        P9(p2, wt, 0.00134934322f)
        P9(p2, wt, -0.00367342844f)
        P9(p2, wt, 0.00573950773f)
        P9(p2, wt, -0.0076224613f)
        P9(p2, wt, 0.00943887047f)
        P9(p2, wt, 1.00167406f)
        P9(p2, wt, 2.83297682f)
        p.x = (l.x > TAIL_TH) ? p1.x : p2.x;
        p.y = (l.y > TAIL_TH) ? p1.y : p2.y;
    }
#undef P9
    return p * x;
}

__device__ __forceinline__ float wave_sum(float v) {  // epilogue only
    v += __shfl_down(v, 32);
    v += __shfl_down(v, 16);
    v += __shfl_down(v, 8);
    v += __shfl_down(v, 4);
    v += __shfl_down(v, 2);
    v += __shfl_down(v, 1);
    return v;
}

// Accumulate samples [s_begin, s_end) for batch-row b (and b+256); leaves
// block-reduced partials {sum0,sq0,sum1,sq1} per k in s_fin[64].
// s_mu/s_sv hold log2e-scaled mean and log2e*sqrt(2*var): softmax in log2
// domain (exp2 = bare v_exp_f32), NO max-subtract (|x| <= ~15 so exp2 is
// overflow-safe and row sums < 2^20).
__device__ __forceinline__ void sg_accumulate(const float* __restrict__ mean,
                                              const float* __restrict__ var,
                                              int b, int s_begin, int s_end,
                                              float (*s_mu)[16], float (*s_sv)[16],
                                              float* s_red, float* s_fin) {
    const int tid = threadIdx.x;

    if (tid < 32) {
        int h = tid >> 4, k = tid & 15;
        int bg = b + 256 * h;
        s_mu[h][k] = LOG2E * mean[bg * 16 + k];
        s_sv[h][k] = (LOG2E * 1.41421356237309515f) * sqrtf(var[bg * 16 + k]);
    }
    __syncthreads();

    f32x2 accs0[8], accq0[8], accs1[8], accq1[8];
#pragma unroll
    for (int kp = 0; kp < 8; kp++) {
        accs0[kp] = (f32x2){0.f, 0.f}; accq0[kp] = (f32x2){0.f, 0.f};
        accs1[kp] = (f32x2){0.f, 0.f}; accq1[kp] = (f32x2){0.f, 0.f};
    }

    const uint32_t base_bk = (uint32_t)(b * 16) * 10000u;

    for (int s = s_begin + tid; s < s_end; s += THREADS) {
        f32x2 e0[8], e1[8];
#pragma unroll
        for (int kp = 0; kp < 8; kp++) {
            uint32_t ia = base_bk + (uint32_t)(kp * 20000) + (uint32_t)s;
            uint32_t ib = ia + 10000u;
            uint32_t a0, a1, b0, b1;
            tf2x32(ia, ia + HALF_N, a0, a1);
            tf2x32(ib, ib + HALF_N, b0, b1);
            f32x2 z0 = erfinv2(u2_from_bits(a0, b0));  // batch b,     k pair
            f32x2 z1 = erfinv2(u2_from_bits(a1, b1));  // batch b+256, k pair
            f32x2 mu0 = *(const f32x2*)&s_mu[0][2 * kp];
            f32x2 sv0 = *(const f32x2*)&s_sv[0][2 * kp];
            f32x2 mu1 = *(const f32x2*)&s_mu[1][2 * kp];
            f32x2 sv1 = *(const f32x2*)&s_sv[1][2 * kp];
            e0[kp] = __builtin_elementwise_fma(z0, sv0, mu0);
            e1[kp] = __builtin_elementwise_fma(z1, sv1, mu1);
        }
        f32x2 sm0 = {0.f, 0.f}, sm1 = {0.f, 0.f};
#pragma unroll
        for (int kp = 0; kp < 8; kp++) {
            f32x2 t0, t1;
            t0.x = __builtin_amdgcn_exp2f(e0[kp].x);
            t0.y = __builtin_amdgcn_exp2f(e0[kp].y);
            t1.x = __builtin_amdgcn_exp2f(e1[kp].x);
            t1.y = __builtin_amdgcn_exp2f(e1[kp].y);
            e0[kp] = t0; sm0 += t0;
            e1[kp] = t1; sm1 += t1;
        }
        float inv0 = __builtin_amdgcn_rcpf(sm0.x + sm0.y);
        float inv1 = __builtin_amdgcn_rcpf(sm1.x + sm1.y);
        f32x2 iv0 = {inv0, inv0}, iv1 = {inv1, inv1};
#pragma unroll
        for (int kp = 0; kp < 8; kp++) {
            f32x2 p0 = e0[kp] * iv0;
            f32x2 p1 = e1[kp] * iv1;
            accs0[kp] += p0;
            accq0[kp] = __builtin_elementwise_fma(p0, p0, accq0[kp]);
            accs1[kp] += p1;
            accq1[kp] = __builtin_elementwise_fma(p1, p1, accq1[kp]);
        }
    }

    const int lane = tid & 63, wave = tid >> 6;
#pragma unroll
    for (int kp = 0; kp < 8; kp++) {
#define RED(val, slot) { float r_ = wave_sum(val); if (lane == 0) s_red[wave * 64 + (slot)] = r_; }
        RED(accs0[kp].x, (2 * kp) * 4 + 0)
        RED(accq0[kp].x, (2 * kp) * 4 + 1)
        RED(accs1[kp].x, (2 * kp) * 4 + 2)
        RED(accq1[kp].x, (2 * kp) * 4 + 3)
        RED(accs0[kp].y, (2 * kp + 1) * 4 + 0)
        RED(accq0[kp].y, (2 * kp + 1) * 4 + 1)
        RED(accs1[kp].y, (2 * kp + 1) * 4 + 2)
        RED(accq1[kp].y, (2 * kp + 1) * 4 + 3)
#undef RED
    }
    __syncthreads();

    if (tid < 64) {
        float t = 0.f;
#pragma unroll
        for (int w = 0; w < WAVES; w++) t += s_red[w * 64 + tid];
        s_fin[tid] = t;
    }
    __syncthreads();
}

// ---- split path: 256*NCH blocks write partials to ws ----
template <int NCH>
__global__ __launch_bounds__(THREADS, 2)
void sg_partial(const float* __restrict__ mean, const float* __restrict__ var,
                float* __restrict__ ws) {
    __shared__ __attribute__((aligned(8))) float s_mu[2][16];
    __shared__ __attribute__((aligned(8))) float s_sv[2][16];
    __shared__ float s_red[WAVES * 64], s_fin[64];
    const int b = blockIdx.x / NCH;       // 0..255
    const int chunk = blockIdx.x % NCH;
    const int c0 = chunk * (NSAMP / NCH);
    sg_accumulate(mean, var, b, c0, c0 + NSAMP / NCH, s_mu, s_sv, s_red, s_fin);
    if (threadIdx.x < 64) ws[blockIdx.x * 64 + threadIdx.x] = s_fin[threadIdx.x];
}

__global__ __launch_bounds__(256)
void sg_finalize(const float* __restrict__ ws, float* __restrict__ out, int nch) {
    int t = blockIdx.x * blockDim.x + threadIdx.x;  // 0..8191
    if (t >= 8192) return;
    int k = t & 15, h = (t >> 4) & 1, b = t >> 5;
    float sum = 0.f, sq = 0.f;
    for (int c = 0; c < nch; c++) {
        const float* p = ws + ((b * nch + c) * 64 + k * 4 + 2 * h);
        sum += p[0];
        sq += p[1];
    }
    float mu = sum * (1.0f / 10000.0f);
    float vr = (sq - sum * mu) * (1.0f / 9999.0f);  // unbiased
    int bg = b + 256 * h;
    out[bg * 16 + k] = mu;
    out[8192 + bg * 16 + k] = vr;
}

// ---- fallback (ws too small): single kernel, one block per b ----
__global__ __launch_bounds__(THREADS, 2)
void sg_kernel(const float* __restrict__ mean, const float* __restrict__ var,
               float* __restrict__ out) {
    __shared__ __attribute__((aligned(8))) float s_mu[2][16];
    __shared__ __attribute__((aligned(8))) float s_sv[2][16];
    __shared__ float s_red[WAVES * 64], s_fin[64];
    const int b = blockIdx.x;
    sg_accumulate(mean, var, b, 0, NSAMP, s_mu, s_sv, s_red, s_fin);
    const int tid = threadIdx.x;
    if (tid < 32) {
        int h = tid >> 4, k = tid & 15;
        float sum = s_fin[k * 4 + 2 * h + 0];
        float sq  = s_fin[k * 4 + 2 * h + 1];
        float mu = sum * (1.0f / 10000.0f);
        float vr = (sq - sum * mu) * (1.0f / 9999.0f);
        int bg = b + 256 * h;
        out[bg * 16 + k] = mu;
        out[8192 + bg * 16 + k] = vr;
    }
}

extern "C" void kernel_launch(void* const* d_in, const int* in_sizes, int n_in,
                              void* d_out, int out_size, void* d_ws, size_t ws_size,
                              hipStream_t stream) {
    const float* mean = (const float*)d_in[0];
    const float* var  = (const float*)d_in[1];
    float* out = (float*)d_out;
    float* ws = (float*)d_ws;
    if (ws_size >= (size_t)256 * 8 * 64 * sizeof(float)) {         // 512 KiB
        sg_partial<8><<<256 * 8, THREADS, 0, stream>>>(mean, var, ws);
        sg_finalize<<<32, 256, 0, stream>>>(ws, out, 8);
    } else if (ws_size >= (size_t)256 * 4 * 64 * sizeof(float)) {  // 256 KiB
        sg_partial<4><<<256 * 4, THREADS, 0, stream>>>(mean, var, ws);
        sg_finalize<<<32, 256, 0, stream>>>(ws, out, 4);
    } else {
        sg_kernel<<<256, THREADS, 0, stream>>>(mean, var, out);
    }
}

// Round 13
// 145.075 us; speedup vs baseline: 1.0745x; 1.0745x over previous
//
#include <hip/hip_runtime.h>
#include <cstdint>
#include <math.h>

// SoftmaxGaussian: out_mean/out_var over 10000 MC softmax samples with
// JAX threefry2x32-exact random draw (key(42), shape (512,16,10000)).
//
// Layout facts:
//   N = 512*16*10000 ; half = 40,960,000 = 256*16*10000
//   flat j=(b*16+k)*10000+s ; threefry block i: counters (i, i+half),
//   key (0,42) -> (z[j=i], z[j=i+half]) => one call yields (b,k,s) AND
//   (b+256,k,s).
//
// R13 (FINAL): revert to the R10 champion (harness 145.0 us). R12's SPLIT=8
// regressed to 155.9 (per-block overhead stopped amortizing: VALUBusy 69->65
// with half the work/block). All axes now bracketed by measurement:
//   block size {64,128,256,512} -> 256 ; SPLIT {1,4,8} -> 4 ;
//   waves/SIMD {2,4,8} -> 4 ; spill-vs-residency -> no-spill ;
//   cooperative/DPP layouts -> slower ; instruction cuts -> applied.
// Residual ~10-25% over the VALU-issue floor is dependency-stall structure
// of the threefry->erfinv->softmax chain; every measured escape returned <=0.

typedef float f32x2 __attribute__((ext_vector_type(2)));

#define NSAMP 10000
#define HALF_N 40960000u
#define THREADS 256
#define WAVES (THREADS / 64)
#define SPLIT 4
#define CHUNK (NSAMP / SPLIT)  // 2500
#define WS_NEEDED (256 * SPLIT * 64 * sizeof(float))  // 262144 B

#define LOG2E 1.44269504088896340736f
#define NLN2 -0.69314718055994530942f
#define SQRT_LN2 0.83255461115769775635f
#define TAIL_TH -7.2134752f  // -5/ln2: main path iff l = log2(1-x^2) > this

__device__ __forceinline__ uint32_t rotl32(uint32_t x, int r) {
    return __builtin_rotateleft32(x, (unsigned)r);  // v_alignbit_b32
}

// JAX threefry2x32, key = (0, 42)
__device__ __forceinline__ void tf2x32(uint32_t x0, uint32_t x1,
                                       uint32_t& o0, uint32_t& o1) {
    const uint32_t ks1 = 42u;
    const uint32_t ks2 = 0x1BD11BDAu ^ 42u;
    x1 += ks1;
#define TF_R(r) { x0 += x1; x1 = rotl32(x1, r); x1 ^= x0; }
    TF_R(13) TF_R(15) TF_R(26) TF_R(6)   x0 += ks1; x1 += ks2 + 1u;
    TF_R(17) TF_R(29) TF_R(16) TF_R(24)  x0 += ks2; x1 += 2u;
    TF_R(13) TF_R(15) TF_R(26) TF_R(6)                x1 += ks1 + 3u;
    TF_R(17) TF_R(29) TF_R(16) TF_R(24)  x0 += ks1; x1 += ks2 + 4u;
    TF_R(13) TF_R(15) TF_R(26) TF_R(6)   x0 += ks2; x1 += 5u;
#undef TF_R
    o0 = x0;
    o1 = x1;
}

// JAX uniform(lo=nextafter(-1,0), hi=1), packed pair; one rounding (= JAX).
__device__ __forceinline__ f32x2 u2_from_bits(uint32_t ba, uint32_t bb) {
    f32x2 f;
    f.x = __uint_as_float((ba >> 9) | 0x3F800000u);
    f.y = __uint_as_float((bb >> 9) | 0x3F800000u);
    f = f - (f32x2){1.0f, 1.0f};  // exact (Sterbenz)
    return __builtin_elementwise_fma(f, (f32x2){2.0f, 2.0f},
                                     (f32x2){-0.99999994f, -0.99999994f});
}

// XLA's ErfInv f32 (Giles 2012), packed pair, wave-uniform tail skip.
// Values identical to the branchless version: tail poly only evaluated
// when some lane needs it (P(any tail in 128 wave-values) ~ 35%).
__device__ __forceinline__ f32x2 erfinv2(f32x2 x) {
    f32x2 t = __builtin_elementwise_fma(-x, x, (f32x2){1.0f, 1.0f});
    f32x2 l;
    l.x = __builtin_amdgcn_logf(t.x);
    l.y = __builtin_amdgcn_logf(t.y);
    f32x2 wm = __builtin_elementwise_fma((f32x2){NLN2, NLN2}, l,
                                         (f32x2){-2.5f, -2.5f});
#define P9(P, W, C) P = __builtin_elementwise_fma(P, W, (f32x2){C, C});
    f32x2 p1 = {2.81022636e-08f, 2.81022636e-08f};
    P9(p1, wm, 3.43273939e-07f)
    P9(p1, wm, -3.5233877e-06f)
    P9(p1, wm, -4.39150654e-06f)
    P9(p1, wm, 0.00021858087f)
    P9(p1, wm, -0.00125372503f)
    P9(p1, wm, -0.00417768164f)
    P9(p1, wm, 0.246640727f)
    P9(p1, wm, 1.50140941f)
    f32x2 p = p1;
    if (__any((l.x < TAIL_TH) || (l.y < TAIL_TH))) {
        f32x2 sq;
        sq.x = __builtin_amdgcn_sqrtf(-l.x);
        sq.y = __builtin_amdgcn_sqrtf(-l.y);
        f32x2 wt = __builtin_elementwise_fma((f32x2){SQRT_LN2, SQRT_LN2}, sq,
                                             (f32x2){-3.0f, -3.0f});
        f32x2 p2 = {-0.000200214257f, -0.000200214257f};
        P9(p2, wt, 0.000100950558f)
        P9(p2, wt, 0.00134934322f)
        P9(p2, wt, -0.00367342844f)
        P9(p2, wt, 0.00573950773f)
        P9(p2, wt, -0.0076224613f)
        P9(p2, wt, 0.00943887047f)
        P9(p2, wt, 1.00167406f)
        P9(p2, wt, 2.83297682f)
        p.x = (l.x > TAIL_TH) ? p1.x : p2.x;
        p.y = (l.y > TAIL_TH) ? p1.y : p2.y;
    }
#undef P9
    return p * x;
}

__device__ __forceinline__ float wave_sum(float v) {  // epilogue only
    v += __shfl_down(v, 32);
    v += __shfl_down(v, 16);
    v += __shfl_down(v, 8);
    v += __shfl_down(v, 4);
    v += __shfl_down(v, 2);
    v += __shfl_down(v, 1);
    return v;
}

// Accumulate samples [s_begin, s_end) for batch-row b (and b+256); leaves
// block-reduced partials {sum0,sq0,sum1,sq1} per k in s_fin[64].
// s_mu/s_sv hold log2e-scaled mean and log2e*sqrt(2*var): softmax in log2
// domain (exp2 = bare v_exp_f32), NO max-subtract (|x| <= ~15 so exp2 is
// overflow-safe and row sums < 2^20).
__device__ __forceinline__ void sg_accumulate(const float* __restrict__ mean,
                                              const float* __restrict__ var,
                                              int b, int s_begin, int s_end,
                                              float (*s_mu)[16], float (*s_sv)[16],
                                              float* s_red, float* s_fin) {
    const int tid = threadIdx.x;

    if (tid < 32) {
        int h = tid >> 4, k = tid & 15;
        int bg = b + 256 * h;
        s_mu[h][k] = LOG2E * mean[bg * 16 + k];
        s_sv[h][k] = (LOG2E * 1.41421356237309515f) * sqrtf(var[bg * 16 + k]);
    }
    __syncthreads();

    f32x2 accs0[8], accq0[8], accs1[8], accq1[8];
#pragma unroll
    for (int kp = 0; kp < 8; kp++) {
        accs0[kp] = (f32x2){0.f, 0.f}; accq0[kp] = (f32x2){0.f, 0.f};
        accs1[kp] = (f32x2){0.f, 0.f}; accq1[kp] = (f32x2){0.f, 0.f};
    }

    const uint32_t base_bk = (uint32_t)(b * 16) * 10000u;

    for (int s = s_begin + tid; s < s_end; s += THREADS) {
        f32x2 e0[8], e1[8];
#pragma unroll
        for (int kp = 0; kp < 8; kp++) {
            uint32_t ia = base_bk + (uint32_t)(kp * 20000) + (uint32_t)s;
            uint32_t ib = ia + 10000u;
            uint32_t a0, a1, b0, b1;
            tf2x32(ia, ia + HALF_N, a0, a1);
            tf2x32(ib, ib + HALF_N, b0, b1);
            f32x2 z0 = erfinv2(u2_from_bits(a0, b0));  // batch b,     k pair
            f32x2 z1 = erfinv2(u2_from_bits(a1, b1));  // batch b+256, k pair
            f32x2 mu0 = *(const f32x2*)&s_mu[0][2 * kp];
            f32x2 sv0 = *(const f32x2*)&s_sv[0][2 * kp];
            f32x2 mu1 = *(const f32x2*)&s_mu[1][2 * kp];
            f32x2 sv1 = *(const f32x2*)&s_sv[1][2 * kp];
            e0[kp] = __builtin_elementwise_fma(z0, sv0, mu0);
            e1[kp] = __builtin_elementwise_fma(z1, sv1, mu1);
        }
        f32x2 sm0 = {0.f, 0.f}, sm1 = {0.f, 0.f};
#pragma unroll
        for (int kp = 0; kp < 8; kp++) {
            f32x2 t0, t1;
            t0.x = __builtin_amdgcn_exp2f(e0[kp].x);
            t0.y = __builtin_amdgcn_exp2f(e0[kp].y);
            t1.x = __builtin_amdgcn_exp2f(e1[kp].x);
            t1.y = __builtin_amdgcn_exp2f(e1[kp].y);
            e0[kp] = t0; sm0 += t0;
            e1[kp] = t1; sm1 += t1;
        }
        float inv0 = __builtin_amdgcn_rcpf(sm0.x + sm0.y);
        float inv1 = __builtin_amdgcn_rcpf(sm1.x + sm1.y);
        f32x2 iv0 = {inv0, inv0}, iv1 = {inv1, inv1};
#pragma unroll
        for (int kp = 0; kp < 8; kp++) {
            f32x2 p0 = e0[kp] * iv0;
            f32x2 p1 = e1[kp] * iv1;
            accs0[kp] += p0;
            accq0[kp] = __builtin_elementwise_fma(p0, p0, accq0[kp]);
            accs1[kp] += p1;
            accq1[kp] = __builtin_elementwise_fma(p1, p1, accq1[kp]);
        }
    }

    const int lane = tid & 63, wave = tid >> 6;
#pragma unroll
    for (int kp = 0; kp < 8; kp++) {
#define RED(val, slot) { float r_ = wave_sum(val); if (lane == 0) s_red[wave * 64 + (slot)] = r_; }
        RED(accs0[kp].x, (2 * kp) * 4 + 0)
        RED(accq0[kp].x, (2 * kp) * 4 + 1)
        RED(accs1[kp].x, (2 * kp) * 4 + 2)
        RED(accq1[kp].x, (2 * kp) * 4 + 3)
        RED(accs0[kp].y, (2 * kp + 1) * 4 + 0)
        RED(accq0[kp].y, (2 * kp + 1) * 4 + 1)
        RED(accs1[kp].y, (2 * kp + 1) * 4 + 2)
        RED(accq1[kp].y, (2 * kp + 1) * 4 + 3)
#undef RED
    }
    __syncthreads();

    if (tid < 64) {
        float t = 0.f;
#pragma unroll
        for (int w = 0; w < WAVES; w++) t += s_red[w * 64 + tid];
        s_fin[tid] = t;
    }
    __syncthreads();
}

// ---- split path: 256*SPLIT blocks write partials to ws ----
__global__ __launch_bounds__(THREADS, 2)
void sg_partial(const float* __restrict__ mean, const float* __restrict__ var,
                float* __restrict__ ws) {
    __shared__ __attribute__((aligned(8))) float s_mu[2][16];
    __shared__ __attribute__((aligned(8))) float s_sv[2][16];
    __shared__ float s_red[WAVES * 64], s_fin[64];
    const int b = blockIdx.x >> 2;       // 0..255
    const int chunk = blockIdx.x & 3;    // 0..SPLIT-1
    sg_accumulate(mean, var, b, chunk * CHUNK, (chunk + 1) * CHUNK,
                  s_mu, s_sv, s_red, s_fin);
    if (threadIdx.x < 64) ws[blockIdx.x * 64 + threadIdx.x] = s_fin[threadIdx.x];
}

__global__ __launch_bounds__(256)
void sg_finalize(const float* __restrict__ ws, float* __restrict__ out) {
    int t = blockIdx.x * blockDim.x + threadIdx.x;  // 0..8191
    if (t >= 8192) return;
    int k = t & 15, h = (t >> 4) & 1, b = t >> 5;
    float sum = 0.f, sq = 0.f;
#pragma unroll
    for (int c = 0; c < SPLIT; c++) {
        const float* p = ws + ((b * SPLIT + c) * 64 + k * 4 + 2 * h);
        sum += p[0];
        sq += p[1];
    }
    float mu = sum * (1.0f / 10000.0f);
    float vr = (sq - sum * mu) * (1.0f / 9999.0f);  // unbiased
    int bg = b + 256 * h;
    out[bg * 16 + k] = mu;
    out[8192 + bg * 16 + k] = vr;
}

// ---- fallback (ws too small): single kernel, one block per b ----
__global__ __launch_bounds__(THREADS, 2)
void sg_kernel(const float* __restrict__ mean, const float* __restrict__ var,
               float* __restrict__ out) {
    __shared__ __attribute__((aligned(8))) float s_mu[2][16];
    __shared__ __attribute__((aligned(8))) float s_sv[2][16];
    __shared__ float s_red[WAVES * 64], s_fin[64];
    const int b = blockIdx.x;
    sg_accumulate(mean, var, b, 0, NSAMP, s_mu, s_sv, s_red, s_fin);
    const int tid = threadIdx.x;
    if (tid < 32) {
        int h = tid >> 4, k = tid & 15;
        float sum = s_fin[k * 4 + 2 * h + 0];
        float sq  = s_fin[k * 4 + 2 * h + 1];
        float mu = sum * (1.0f / 10000.0f);
        float vr = (sq - sum * mu) * (1.0f / 9999.0f);
        int bg = b + 256 * h;
        out[bg * 16 + k] = mu;
        out[8192 + bg * 16 + k] = vr;
    }
}

extern "C" void kernel_launch(void* const* d_in, const int* in_sizes, int n_in,
                              void* d_out, int out_size, void* d_ws, size_t ws_size,
                              hipStream_t stream) {
    const float* mean = (const float*)d_in[0];
    const float* var  = (const float*)d_in[1];
    float* out = (float*)d_out;
    if (ws_size >= WS_NEEDED) {
        float* ws = (float*)d_ws;
        sg_partial<<<256 * SPLIT, THREADS, 0, stream>>>(mean, var, ws);
        sg_finalize<<<32, 256, 0, stream>>>(ws, out);
    } else {
        sg_kernel<<<256, THREADS, 0, stream>>>(mean, var, out);
    }
}